// Round 1
// baseline (4298.480 us; speedup 1.0000x reference)
//
#include <hip/hip_runtime.h>
#include <hip/hip_bf16.h>
#include <math.h>

#define HID 256
#define HEADS 8

// ---------------- CSR build ----------------

__global__ __launch_bounds__(256) void deg_count_kernel(const int* __restrict__ ei,
    int* __restrict__ deg, int E, int Etot) {
  int idx = blockIdx.x * 256 + threadIdx.x;
  if (idx >= Etot) return;
  int d = (idx < E) ? ei[E + idx] : (idx - E);
  atomicAdd(&deg[d], 1);
}

__global__ __launch_bounds__(1024) void scan_kernel(const int* __restrict__ deg,
    int* __restrict__ rowptr, int* __restrict__ cursor, int N) {
  __shared__ int sums[1024];
  int t = threadIdx.x;
  int chunk = (N + 1023) / 1024;
  int lo = t * chunk, hi = min(N, lo + chunk);
  int s = 0;
  for (int i = lo; i < hi; ++i) s += deg[i];
  sums[t] = s;
  __syncthreads();
  for (int off = 1; off < 1024; off <<= 1) {
    int v = (t >= off) ? sums[t - off] : 0;
    __syncthreads();
    sums[t] += v;
    __syncthreads();
  }
  int prefix = (t == 0) ? 0 : sums[t - 1];
  for (int i = lo; i < hi; ++i) {
    rowptr[i] = prefix;
    cursor[i] = prefix;
    prefix += deg[i];
  }
  if (t == 1023) rowptr[N] = sums[1023];
}

__global__ __launch_bounds__(256) void scatter_kernel(const int* __restrict__ ei,
    int* __restrict__ cursor, int* __restrict__ csr_src, int E, int Etot) {
  int idx = blockIdx.x * 256 + threadIdx.x;
  if (idx >= Etot) return;
  int s, d;
  if (idx < E) { s = ei[idx]; d = ei[E + idx]; }
  else { s = idx - E; d = s; }
  int pos = atomicAdd(&cursor[d], 1);
  csr_src[pos] = s;
}

// ---------------- fp32 tiled GEMM: C[M,256] = A[M,K] @ B[K,256] ----------------
// grid: (256/64, ceil(M/64)); block 256; 4x4 microtile per thread.

__global__ __launch_bounds__(256) void gemm_f32(const float* __restrict__ A,
    const float* __restrict__ B, float* __restrict__ C, int M, int K) {
  __shared__ __align__(16) float As[16][68];
  __shared__ __align__(16) float Bs[16][68];
  int tid = threadIdx.x;
  int tx = tid & 15, ty = tid >> 4;
  int row0 = blockIdx.y * 64, col0 = blockIdx.x * 64;
  float acc[4][4] = {{0.f}};
  int am = tid >> 4;   // 0..15
  int ak = tid & 15;   // 0..15
  int bn = tid & 63;   // 0..63
  int bk = tid >> 6;   // 0..3

  for (int k0 = 0; k0 < K; k0 += 16) {
#pragma unroll
    for (int i = 0; i < 4; ++i) {
      int m = am + 16 * i;
      int r = row0 + m;
      int k = k0 + ak;
      As[ak][m] = (r < M && k < K) ? A[(size_t)r * K + k] : 0.f;
    }
#pragma unroll
    for (int i = 0; i < 4; ++i) {
      int k = bk + 4 * i;
      int kk = k0 + k;
      Bs[k][bn] = (kk < K) ? B[(size_t)kk * HID + col0 + bn] : 0.f;
    }
    __syncthreads();
#pragma unroll
    for (int kk = 0; kk < 16; ++kk) {
      float4 a4 = *(const float4*)&As[kk][ty * 4];
      float4 b4 = *(const float4*)&Bs[kk][tx * 4];
      float av[4] = {a4.x, a4.y, a4.z, a4.w};
      float bv[4] = {b4.x, b4.y, b4.z, b4.w};
#pragma unroll
      for (int i = 0; i < 4; ++i)
#pragma unroll
        for (int j = 0; j < 4; ++j) acc[i][j] += av[i] * bv[j];
    }
    __syncthreads();
  }
#pragma unroll
  for (int i = 0; i < 4; ++i) {
    int r = row0 + ty * 4 + i;
    if (r < M) {
      float4 v = make_float4(acc[i][0], acc[i][1], acc[i][2], acc[i][3]);
      *(float4*)&C[(size_t)r * HID + col0 + tx * 4] = v;
    }
  }
}

// ---------------- per-node attention logits ----------------
// one thread per (node, head): es = <H[n,h,:], a_src[h,:]>, ed likewise.

__global__ __launch_bounds__(256) void node_logits_kernel(const float* __restrict__ H,
    const float* __restrict__ a_src, const float* __restrict__ a_dst,
    float* __restrict__ en_src, float* __restrict__ en_dst, int N) {
  int idx = blockIdx.x * 256 + threadIdx.x;
  if (idx >= N * HEADS) return;
  int n = idx >> 3, h = idx & 7;
  const float4* Hv = (const float4*)(H + (size_t)n * HID + h * 32);
  const float4* S4 = (const float4*)(a_src + h * 32);
  const float4* D4 = (const float4*)(a_dst + h * 32);
  float es = 0.f, ed = 0.f;
#pragma unroll
  for (int i = 0; i < 8; ++i) {
    float4 v = Hv[i], sv = S4[i], dv = D4[i];
    es += v.x * sv.x + v.y * sv.y + v.z * sv.z + v.w * sv.w;
    ed += v.x * dv.x + v.y * dv.y + v.z * dv.z + v.w * dv.w;
  }
  en_src[idx] = es;
  en_dst[idx] = ed;
}

// ---------------- fused online-softmax aggregation ----------------
// block per dst node; 256 threads = 256 channels; single pass over incoming edges.

__global__ __launch_bounds__(256) void gat_agg_kernel(const float* __restrict__ H,
    const float* __restrict__ en_src, const float* __restrict__ en_dst,
    const int* __restrict__ rowptr, const int* __restrict__ csr_src,
    const float* __restrict__ bias, float* __restrict__ out, int apply_elu) {
  __shared__ int s_src[256];
  int n = blockIdx.x;
  int c = threadIdx.x;
  int hd = c >> 5;
  float ed = en_dst[n * HEADS + hd];
  int beg = rowptr[n], end = rowptr[n + 1];
  float m = -INFINITY, s = 0.f, acc = 0.f;
  for (int cs = beg; cs < end; cs += 256) {
    int cnt = min(256, end - cs);
    __syncthreads();
    if (c < cnt) s_src[c] = csr_src[cs + c];
    __syncthreads();
    int src0 = s_src[0];
    float hv = H[(size_t)src0 * HID + c];
    float es = en_src[src0 * HEADS + hd];
    for (int i = 0; i < cnt; ++i) {
      float hv_c = hv, es_c = es;
      if (i + 1 < cnt) {
        int s2 = s_src[i + 1];
        hv = H[(size_t)s2 * HID + c];
        es = en_src[s2 * HEADS + hd];
      }
      float e = es_c + ed;
      e = (e > 0.f) ? e : 0.2f * e;
      float mn = fmaxf(m, e);
      float sc = __expf(m - mn);   // first iter: exp(-inf) = 0
      float w = __expf(e - mn);
      s = s * sc + w;
      acc = acc * sc + w * hv_c;
      m = mn;
    }
  }
  float o = acc / (s + 1e-16f) + bias[c];
  if (apply_elu) o = (o > 0.f) ? o : expm1f(o);
  out[(size_t)n * HID + c] = o;
}

// ---------------- JK max + final linear + log_softmax ----------------
// block = 256 threads = 4 nodes x 64 lanes; Wf staged in LDS.

__global__ __launch_bounds__(256) void final_kernel(const float* __restrict__ h0,
    const float* __restrict__ h1, const float* __restrict__ h2,
    const float* __restrict__ Wf, const float* __restrict__ bf,
    float* __restrict__ out, int N) {
  __shared__ float Wfs[HID * 40];
  __shared__ float jks[4][HID];
  int tid = threadIdx.x;
  for (int i = tid; i < HID * 40; i += 256) Wfs[i] = Wf[i];
  int sub = tid >> 6, lane = tid & 63;
  int n = blockIdx.x * 4 + sub;
  if (n < N) {
    const float4* p0 = (const float4*)(h0 + (size_t)n * HID);
    const float4* p1 = (const float4*)(h1 + (size_t)n * HID);
    const float4* p2 = (const float4*)(h2 + (size_t)n * HID);
    float4 a = p0[lane], b = p1[lane], cc = p2[lane];
    float4 r;
    r.x = fmaxf(fmaxf(a.x, b.x), cc.x);
    r.y = fmaxf(fmaxf(a.y, b.y), cc.y);
    r.z = fmaxf(fmaxf(a.z, b.z), cc.z);
    r.w = fmaxf(fmaxf(a.w, b.w), cc.w);
    *(float4*)&jks[sub][lane * 4] = r;
  }
  __syncthreads();
  float logit = -INFINITY;
  if (lane < 40 && n < N) {
    float accv = bf[lane];
#pragma unroll 8
    for (int k = 0; k < HID; ++k) accv += jks[sub][k] * Wfs[k * 40 + lane];
    logit = accv;
  }
  float mx = logit;
#pragma unroll
  for (int off = 32; off > 0; off >>= 1) mx = fmaxf(mx, __shfl_down(mx, off));
  mx = __shfl(mx, 0);
  float ex = (lane < 40 && n < N) ? __expf(logit - mx) : 0.f;
  float sm = ex;
#pragma unroll
  for (int off = 32; off > 0; off >>= 1) sm += __shfl_down(sm, off);
  sm = __shfl(sm, 0);
  if (lane < 40 && n < N) out[(size_t)n * 40 + lane] = logit - mx - __logf(sm);
}

// ---------------- launch ----------------

extern "C" void kernel_launch(void* const* d_in, const int* in_sizes, int n_in,
                              void* d_out, int out_size, void* d_ws, size_t ws_size,
                              hipStream_t stream) {
  (void)n_in; (void)out_size; (void)ws_size;
  const float* x   = (const float*)d_in[0];
  const int*   ei  = (const int*)d_in[1];
  const float* W0  = (const float*)d_in[2];
  const float* as0 = (const float*)d_in[3];
  const float* ad0 = (const float*)d_in[4];
  const float* b0  = (const float*)d_in[5];
  const float* W1  = (const float*)d_in[6];
  const float* as1 = (const float*)d_in[7];
  const float* ad1 = (const float*)d_in[8];
  const float* b1  = (const float*)d_in[9];
  const float* W2  = (const float*)d_in[10];
  const float* as2 = (const float*)d_in[11];
  const float* ad2 = (const float*)d_in[12];
  const float* b2  = (const float*)d_in[13];
  const float* Wf  = (const float*)d_in[14];
  const float* bf  = (const float*)d_in[15];
  float* out = (float*)d_out;

  const int E = in_sizes[1] / 2;
  const int IN_CH = in_sizes[2] / HID;      // 500
  const int N = in_sizes[0] / IN_CH;        // 100000
  const int Etot = E + N;
  const size_t NM = (size_t)N * HID;
  const size_t NH = (size_t)N * HEADS;

  float* ws   = (float*)d_ws;
  float* Htmp = ws;
  float* h0   = ws + NM;
  float* h1   = ws + 2 * NM;
  float* h2   = ws + 3 * NM;
  float* en_s = ws + 4 * NM;
  float* en_d = en_s + NH;
  int* rowptr  = (int*)(en_d + NH);
  int* deg     = rowptr + (N + 1);
  int* cursor  = deg + N;
  int* csr_src = cursor + N;

  hipMemsetAsync(deg, 0, sizeof(int) * N, stream);
  int ebl = (Etot + 255) / 256;
  deg_count_kernel<<<ebl, 256, 0, stream>>>(ei, deg, E, Etot);
  scan_kernel<<<1, 1024, 0, stream>>>(deg, rowptr, cursor, N);
  scatter_kernel<<<ebl, 256, 0, stream>>>(ei, cursor, csr_src, E, Etot);

  dim3 ggrid(HID / 64, (N + 63) / 64);
  int lblocks = (N * HEADS + 255) / 256;

  // layer 0
  gemm_f32<<<ggrid, 256, 0, stream>>>(x, W0, Htmp, N, IN_CH);
  node_logits_kernel<<<lblocks, 256, 0, stream>>>(Htmp, as0, ad0, en_s, en_d, N);
  gat_agg_kernel<<<N, 256, 0, stream>>>(Htmp, en_s, en_d, rowptr, csr_src, b0, h0, 1);
  // layer 1
  gemm_f32<<<ggrid, 256, 0, stream>>>(h0, W1, Htmp, N, HID);
  node_logits_kernel<<<lblocks, 256, 0, stream>>>(Htmp, as1, ad1, en_s, en_d, N);
  gat_agg_kernel<<<N, 256, 0, stream>>>(Htmp, en_s, en_d, rowptr, csr_src, b1, h1, 1);
  // layer 2
  gemm_f32<<<ggrid, 256, 0, stream>>>(h1, W2, Htmp, N, HID);
  node_logits_kernel<<<lblocks, 256, 0, stream>>>(Htmp, as2, ad2, en_s, en_d, N);
  gat_agg_kernel<<<N, 256, 0, stream>>>(Htmp, en_s, en_d, rowptr, csr_src, b2, h2, 0);

  final_kernel<<<(N + 3) / 4, 256, 0, stream>>>(h0, h1, h2, Wf, bf, out, N);
}

// Round 2
// 3795.483 us; speedup vs baseline: 1.1325x; 1.1325x over previous
//
#include <hip/hip_runtime.h>
#include <hip/hip_bf16.h>
#include <math.h>

#define HID 256
#define HEADS 8
#define CHUNK 128

typedef __attribute__((ext_vector_type(8))) short short8;
typedef __attribute__((ext_vector_type(4))) float floatx4;

// ---------------- CSR build ----------------

__global__ __launch_bounds__(256) void deg_count_kernel(const int* __restrict__ ei,
    int* __restrict__ deg, int E, int Etot) {
  int idx = blockIdx.x * 256 + threadIdx.x;
  if (idx >= Etot) return;
  int d = (idx < E) ? ei[E + idx] : (idx - E);
  atomicAdd(&deg[d], 1);
}

__global__ __launch_bounds__(1024) void scan_kernel(const int* __restrict__ deg,
    int* __restrict__ rowptr, int* __restrict__ cursor, int N) {
  __shared__ int sums[1024];
  int t = threadIdx.x;
  int chunk = (N + 1023) / 1024;
  int lo = t * chunk, hi = min(N, lo + chunk);
  int s = 0;
  for (int i = lo; i < hi; ++i) s += deg[i];
  sums[t] = s;
  __syncthreads();
  for (int off = 1; off < 1024; off <<= 1) {
    int v = (t >= off) ? sums[t - off] : 0;
    __syncthreads();
    sums[t] += v;
    __syncthreads();
  }
  int prefix = (t == 0) ? 0 : sums[t - 1];
  for (int i = lo; i < hi; ++i) {
    rowptr[i] = prefix;
    cursor[i] = prefix;
    prefix += deg[i];
  }
  if (t == 1023) rowptr[N] = sums[1023];
}

__global__ __launch_bounds__(256) void scatter_kernel(const int* __restrict__ ei,
    int* __restrict__ cursor, int* __restrict__ csr_src, int E, int Etot) {
  int idx = blockIdx.x * 256 + threadIdx.x;
  if (idx >= Etot) return;
  int s, d;
  if (idx < E) { s = ei[idx]; d = ei[E + idx]; }
  else { s = idx - E; d = s; }
  int pos = atomicAdd(&cursor[d], 1);
  csr_src[pos] = s;
}

// ---------------- weight fp32 -> bf16 ----------------

__global__ __launch_bounds__(256) void conv_bf16_kernel(const float* __restrict__ src,
    __hip_bfloat16* __restrict__ dst, int n) {
  int i = blockIdx.x * 256 + threadIdx.x;
  if (i < n) dst[i] = __float2bfloat16(src[i]);
}

// ---------------- bf16 MFMA GEMM: C[M,256](bf16) = A[M,K](fp32) @ B[K,256](bf16) ----
// tile 64x64, BK=32, block 256 (4 waves, each wave owns a 16-col strip, 4 row-blocks)

__global__ __launch_bounds__(256) void gemm_bf16(const float* __restrict__ A,
    const __hip_bfloat16* __restrict__ B, __hip_bfloat16* __restrict__ C,
    int M, int K) {
  __shared__ __align__(16) __hip_bfloat16 As[64][40];  // [m][k], pad to 40 vs bank conflicts
  __shared__ __align__(16) __hip_bfloat16 Bs[64][40];  // [n][k] (transposed)
  int tid = threadIdx.x;
  int wave = tid >> 6, lane = tid & 63;
  int quad = lane >> 4, mr = lane & 15;
  int row0 = blockIdx.y * 64, col0 = blockIdx.x * 64;
  floatx4 acc[4] = {};
  int arow = tid >> 2;          // 0..63
  int akc = (tid & 3) * 8;      // 0,8,16,24
  int bn = tid & 63;
  int bkg = (tid >> 6) * 8;     // 0,8,16,24

  for (int k0 = 0; k0 < K; k0 += 32) {
    // stage A tile (fp32 -> bf16)
    bool rok = (row0 + arow) < M;
    const float* Ap = A + (size_t)(row0 + arow) * K + k0 + akc;
    if (rok && (k0 + akc + 7) < K) {
      float4 v0 = *(const float4*)(Ap);
      float4 v1 = *(const float4*)(Ap + 4);
      As[arow][akc + 0] = __float2bfloat16(v0.x);
      As[arow][akc + 1] = __float2bfloat16(v0.y);
      As[arow][akc + 2] = __float2bfloat16(v0.z);
      As[arow][akc + 3] = __float2bfloat16(v0.w);
      As[arow][akc + 4] = __float2bfloat16(v1.x);
      As[arow][akc + 5] = __float2bfloat16(v1.y);
      As[arow][akc + 6] = __float2bfloat16(v1.z);
      As[arow][akc + 7] = __float2bfloat16(v1.w);
    } else {
#pragma unroll
      for (int i = 0; i < 8; ++i) {
        int k = k0 + akc + i;
        As[arow][akc + i] = (rok && k < K) ? __float2bfloat16(Ap[i]) : __float2bfloat16(0.f);
      }
    }
    // stage B tile transposed: Bs[n][k] = B[k0+k][col0+n]
#pragma unroll
    for (int i = 0; i < 8; ++i) {
      int k = bkg + i;
      int kk = k0 + k;
      Bs[bn][k] = (kk < K) ? B[(size_t)kk * HID + col0 + bn] : __float2bfloat16(0.f);
    }
    __syncthreads();
    short8 bf = *(const short8*)&Bs[wave * 16 + mr][quad * 8];
#pragma unroll
    for (int r = 0; r < 4; ++r) {
      short8 af = *(const short8*)&As[r * 16 + mr][quad * 8];
      acc[r] = __builtin_amdgcn_mfma_f32_16x16x32_bf16(af, bf, acc[r], 0, 0, 0);
    }
    __syncthreads();
  }
  int col = col0 + wave * 16 + mr;
#pragma unroll
  for (int r = 0; r < 4; ++r) {
#pragma unroll
    for (int i = 0; i < 4; ++i) {
      int row = row0 + r * 16 + quad * 4 + i;
      if (row < M) C[(size_t)row * HID + col] = __float2bfloat16(acc[r][i]);
    }
  }
}

// ---------------- per-node attention logits (bf16 H) ----------------

__global__ __launch_bounds__(256) void node_logits_kernel(const __hip_bfloat16* __restrict__ H,
    const float* __restrict__ a_src, const float* __restrict__ a_dst,
    float* __restrict__ en_src, float* __restrict__ en_dst, int N) {
  int idx = blockIdx.x * 256 + threadIdx.x;
  if (idx >= N * HEADS) return;
  int n = idx >> 3, h = idx & 7;
  const __hip_bfloat16* Hp = H + (size_t)n * HID + h * 32;
  const float* S = a_src + h * 32;
  const float* D = a_dst + h * 32;
  float es = 0.f, ed = 0.f;
#pragma unroll
  for (int i = 0; i < 32; ++i) {
    float v = __bfloat162float(Hp[i]);
    es += v * S[i];
    ed += v * D[i];
  }
  en_src[idx] = es;
  en_dst[idx] = ed;
}

// ---------------- per-(node,head) softmax stats: m and 1/sum ----------------

__global__ __launch_bounds__(256) void stats_kernel(const float* __restrict__ en_src,
    const float* __restrict__ en_dst, const int* __restrict__ rowptr,
    const int* __restrict__ csr_src, float* __restrict__ mstat,
    float* __restrict__ rstat, int N) {
  int idx = blockIdx.x * 256 + threadIdx.x;
  if (idx >= N * HEADS) return;
  int n = idx >> 3, h = idx & 7;
  float ed = en_dst[idx];
  int beg = rowptr[n], end = rowptr[n + 1];
  float m = -INFINITY, s = 0.f;
  int sp = csr_src[beg];               // deg >= 1 (self-loop)
  for (int e = beg; e < end; ++e) {
    int sc = sp;
    if (e + 1 < end) sp = csr_src[e + 1];
    float es = en_src[sc * HEADS + h];
    float v = es + ed;
    v = (v > 0.f) ? v : 0.2f * v;
    float mn = fmaxf(m, v);
    s = s * __expf(m - mn) + __expf(v - mn);
    m = mn;
  }
  mstat[idx] = m;
  rstat[idx] = 1.f / (s + 1e-16f);
}

// ---------------- slim aggregation: out[dst] = sum_e w[e,h] * H[src_e] ----------------
// block per dst node; 256 threads = 256 channels; weights precomputed per chunk in LDS.

__global__ __launch_bounds__(256) void gat_agg_kernel(const __hip_bfloat16* __restrict__ H,
    const float* __restrict__ en_src, const float* __restrict__ en_dst,
    const float* __restrict__ mstat, const float* __restrict__ rstat,
    const int* __restrict__ rowptr, const int* __restrict__ csr_src,
    const float* __restrict__ bias, float* __restrict__ out, int apply_elu) {
  __shared__ int s_src[CHUNK];
  __shared__ float s_w[CHUNK * HEADS];
  __shared__ float s_ed[HEADS], s_m[HEADS], s_rs[HEADS];
  int n = blockIdx.x;
  int t = threadIdx.x;
  if (t < HEADS) {
    s_ed[t] = en_dst[n * HEADS + t];
    s_m[t] = mstat[n * HEADS + t];
    s_rs[t] = rstat[n * HEADS + t];
  }
  int beg = rowptr[n], end = rowptr[n + 1];
  int hd = t >> 5;
  float acc = 0.f;
  for (int cs = beg; cs < end; cs += CHUNK) {
    int cnt = min(CHUNK, end - cs);
    __syncthreads();
    if (t < cnt) s_src[t] = csr_src[cs + t];
    __syncthreads();
    // per-(edge,head) weights
    for (int j = t; j < cnt * HEADS; j += 256) {
      int i = j >> 3, h = j & 7;
      int sN = s_src[i];
      float es = en_src[sN * HEADS + h];
      float v = es + s_ed[h];
      v = (v > 0.f) ? v : 0.2f * v;
      s_w[j] = __expf(v - s_m[h]) * s_rs[h];
    }
    __syncthreads();
    // weighted gather-accumulate
    int src0 = s_src[0];
    float hv = __bfloat162float(H[(size_t)src0 * HID + t]);
    for (int i = 0; i < cnt; ++i) {
      float hv_c = hv;
      if (i + 1 < cnt) {
        int s2 = s_src[i + 1];
        hv = __bfloat162float(H[(size_t)s2 * HID + t]);
      }
      acc += s_w[i * HEADS + hd] * hv_c;
    }
  }
  float o = acc + bias[t];
  if (apply_elu) o = (o > 0.f) ? o : expm1f(o);
  out[(size_t)n * HID + t] = o;
}

// ---------------- JK max + final linear + log_softmax ----------------

__global__ __launch_bounds__(256) void final_kernel(const float* __restrict__ h0,
    const float* __restrict__ h1, const float* __restrict__ h2,
    const float* __restrict__ Wf, const float* __restrict__ bf,
    float* __restrict__ out, int N) {
  __shared__ float Wfs[HID * 40];
  __shared__ float jks[4][HID];
  int tid = threadIdx.x;
  for (int i = tid; i < HID * 40; i += 256) Wfs[i] = Wf[i];
  int sub = tid >> 6, lane = tid & 63;
  int n = blockIdx.x * 4 + sub;
  if (n < N) {
    const float4* p0 = (const float4*)(h0 + (size_t)n * HID);
    const float4* p1 = (const float4*)(h1 + (size_t)n * HID);
    const float4* p2 = (const float4*)(h2 + (size_t)n * HID);
    float4 a = p0[lane], b = p1[lane], cc = p2[lane];
    float4 r;
    r.x = fmaxf(fmaxf(a.x, b.x), cc.x);
    r.y = fmaxf(fmaxf(a.y, b.y), cc.y);
    r.z = fmaxf(fmaxf(a.z, b.z), cc.z);
    r.w = fmaxf(fmaxf(a.w, b.w), cc.w);
    *(float4*)&jks[sub][lane * 4] = r;
  }
  __syncthreads();
  float logit = -INFINITY;
  if (lane < 40 && n < N) {
    float accv = bf[lane];
#pragma unroll 8
    for (int k = 0; k < HID; ++k) accv += jks[sub][k] * Wfs[k * 40 + lane];
    logit = accv;
  }
  float mx = logit;
#pragma unroll
  for (int off = 32; off > 0; off >>= 1) mx = fmaxf(mx, __shfl_down(mx, off));
  mx = __shfl(mx, 0);
  float ex = (lane < 40 && n < N) ? __expf(logit - mx) : 0.f;
  float sm = ex;
#pragma unroll
  for (int off = 32; off > 0; off >>= 1) sm += __shfl_down(sm, off);
  sm = __shfl(sm, 0);
  if (lane < 40 && n < N) out[(size_t)n * 40 + lane] = logit - mx - __logf(sm);
}

// ---------------- launch ----------------

extern "C" void kernel_launch(void* const* d_in, const int* in_sizes, int n_in,
                              void* d_out, int out_size, void* d_ws, size_t ws_size,
                              hipStream_t stream) {
  (void)n_in; (void)out_size; (void)ws_size;
  const float* x   = (const float*)d_in[0];
  const int*   ei  = (const int*)d_in[1];
  const float* W0  = (const float*)d_in[2];
  const float* as0 = (const float*)d_in[3];
  const float* ad0 = (const float*)d_in[4];
  const float* b0  = (const float*)d_in[5];
  const float* W1  = (const float*)d_in[6];
  const float* as1 = (const float*)d_in[7];
  const float* ad1 = (const float*)d_in[8];
  const float* b1  = (const float*)d_in[9];
  const float* W2  = (const float*)d_in[10];
  const float* as2 = (const float*)d_in[11];
  const float* ad2 = (const float*)d_in[12];
  const float* b2  = (const float*)d_in[13];
  const float* Wf  = (const float*)d_in[14];
  const float* bf  = (const float*)d_in[15];
  float* out = (float*)d_out;

  const int E = in_sizes[1] / 2;
  const int IN_CH = in_sizes[2] / HID;      // 500
  const int N = in_sizes[0] / IN_CH;        // 100000
  const int Etot = E + N;
  const size_t NM = (size_t)N * HID;
  const size_t NH = (size_t)N * HEADS;

  __hip_bfloat16* Htb = (__hip_bfloat16*)d_ws;       // NM bf16
  float* fbase = (float*)(Htb + NM);
  float* h0   = fbase;
  float* h1   = fbase + NM;
  float* h2   = fbase + 2 * NM;
  float* en_s = fbase + 3 * NM;
  float* en_d = en_s + NH;
  float* mst  = en_d + NH;
  float* rst  = mst + NH;
  int* rowptr  = (int*)(rst + NH);
  int* deg     = rowptr + (N + 1);
  int* cursor  = deg + N;
  int* csr_src = cursor + N;
  __hip_bfloat16* Wb0 = (__hip_bfloat16*)(csr_src + Etot);
  __hip_bfloat16* Wb1 = Wb0 + (size_t)IN_CH * HID;
  __hip_bfloat16* Wb2 = Wb1 + HID * HID;

  hipMemsetAsync(deg, 0, sizeof(int) * N, stream);
  int ebl = (Etot + 255) / 256;
  deg_count_kernel<<<ebl, 256, 0, stream>>>(ei, deg, E, Etot);
  scan_kernel<<<1, 1024, 0, stream>>>(deg, rowptr, cursor, N);
  scatter_kernel<<<ebl, 256, 0, stream>>>(ei, cursor, csr_src, E, Etot);

  conv_bf16_kernel<<<(IN_CH * HID + 255) / 256, 256, 0, stream>>>(W0, Wb0, IN_CH * HID);
  conv_bf16_kernel<<<(HID * HID + 255) / 256, 256, 0, stream>>>(W1, Wb1, HID * HID);
  conv_bf16_kernel<<<(HID * HID + 255) / 256, 256, 0, stream>>>(W2, Wb2, HID * HID);

  dim3 ggrid(HID / 64, (N + 63) / 64);
  int lblocks = (N * HEADS + 255) / 256;

  // layer 0
  gemm_bf16<<<ggrid, 256, 0, stream>>>(x, Wb0, Htb, N, IN_CH);
  node_logits_kernel<<<lblocks, 256, 0, stream>>>(Htb, as0, ad0, en_s, en_d, N);
  stats_kernel<<<lblocks, 256, 0, stream>>>(en_s, en_d, rowptr, csr_src, mst, rst, N);
  gat_agg_kernel<<<N, 256, 0, stream>>>(Htb, en_s, en_d, mst, rst, rowptr, csr_src, b0, h0, 1);
  // layer 1
  gemm_bf16<<<ggrid, 256, 0, stream>>>(h0, Wb1, Htb, N, HID);
  node_logits_kernel<<<lblocks, 256, 0, stream>>>(Htb, as1, ad1, en_s, en_d, N);
  stats_kernel<<<lblocks, 256, 0, stream>>>(en_s, en_d, rowptr, csr_src, mst, rst, N);
  gat_agg_kernel<<<N, 256, 0, stream>>>(Htb, en_s, en_d, mst, rst, rowptr, csr_src, b1, h1, 1);
  // layer 2
  gemm_bf16<<<ggrid, 256, 0, stream>>>(h1, Wb2, Htb, N, HID);
  node_logits_kernel<<<lblocks, 256, 0, stream>>>(Htb, as2, ad2, en_s, en_d, N);
  stats_kernel<<<lblocks, 256, 0, stream>>>(en_s, en_d, rowptr, csr_src, mst, rst, N);
  gat_agg_kernel<<<N, 256, 0, stream>>>(Htb, en_s, en_d, mst, rst, rowptr, csr_src, b2, h2, 0);

  final_kernel<<<(N + 3) / 4, 256, 0, stream>>>(h0, h1, h2, Wf, bf, out, N);
}

// Round 3
// 2532.073 us; speedup vs baseline: 1.6976x; 1.4990x over previous
//
#include <hip/hip_runtime.h>
#include <hip/hip_bf16.h>
#include <math.h>

#define HID 256
#define HEADS 8

typedef __attribute__((ext_vector_type(8))) short short8;
typedef __attribute__((ext_vector_type(4))) float floatx4;

// ---------------- CSR build ----------------

__global__ __launch_bounds__(256) void deg_count_kernel(const int* __restrict__ ei,
    int* __restrict__ deg, int E, int Etot) {
  int idx = blockIdx.x * 256 + threadIdx.x;
  if (idx >= Etot) return;
  int d = (idx < E) ? ei[E + idx] : (idx - E);
  atomicAdd(&deg[d], 1);
}

__global__ __launch_bounds__(1024) void scan_kernel(const int* __restrict__ deg,
    int* __restrict__ rowptr, int* __restrict__ cursor, int N) {
  __shared__ int sums[1024];
  int t = threadIdx.x;
  int chunk = (N + 1023) / 1024;
  int lo = t * chunk, hi = min(N, lo + chunk);
  int s = 0;
  for (int i = lo; i < hi; ++i) s += deg[i];
  sums[t] = s;
  __syncthreads();
  for (int off = 1; off < 1024; off <<= 1) {
    int v = (t >= off) ? sums[t - off] : 0;
    __syncthreads();
    sums[t] += v;
    __syncthreads();
  }
  int prefix = (t == 0) ? 0 : sums[t - 1];
  for (int i = lo; i < hi; ++i) {
    rowptr[i] = prefix;
    cursor[i] = prefix;
    prefix += deg[i];
  }
  if (t == 1023) rowptr[N] = sums[1023];
}

__global__ __launch_bounds__(256) void scatter_kernel(const int* __restrict__ ei,
    int* __restrict__ cursor, int* __restrict__ csr_src, int E, int Etot) {
  int idx = blockIdx.x * 256 + threadIdx.x;
  if (idx >= Etot) return;
  int s, d;
  if (idx < E) { s = ei[idx]; d = ei[E + idx]; }
  else { s = idx - E; d = s; }
  int pos = atomicAdd(&cursor[d], 1);
  csr_src[pos] = s;
}

// ---------------- weight fp32 -> bf16 ----------------

__global__ __launch_bounds__(256) void conv_bf16_kernel(const float* __restrict__ src,
    __hip_bfloat16* __restrict__ dst, int n) {
  int i = blockIdx.x * 256 + threadIdx.x;
  if (i < n) dst[i] = __float2bfloat16(src[i]);
}

// ---------------- bf16 MFMA GEMM: C[M,256](bf16) = A[M,K](fp32) @ B[K,256](bf16) ----

__global__ __launch_bounds__(256) void gemm_bf16(const float* __restrict__ A,
    const __hip_bfloat16* __restrict__ B, __hip_bfloat16* __restrict__ C,
    int M, int K) {
  __shared__ __align__(16) __hip_bfloat16 As[64][40];
  __shared__ __align__(16) __hip_bfloat16 Bs[64][40];
  int tid = threadIdx.x;
  int wave = tid >> 6, lane = tid & 63;
  int quad = lane >> 4, mr = lane & 15;
  int row0 = blockIdx.y * 64, col0 = blockIdx.x * 64;
  floatx4 acc[4] = {};
  int arow = tid >> 2;
  int akc = (tid & 3) * 8;
  int bn = tid & 63;
  int bkg = (tid >> 6) * 8;

  for (int k0 = 0; k0 < K; k0 += 32) {
    bool rok = (row0 + arow) < M;
    const float* Ap = A + (size_t)(row0 + arow) * K + k0 + akc;
    if (rok && (k0 + akc + 7) < K) {
      float4 v0 = *(const float4*)(Ap);
      float4 v1 = *(const float4*)(Ap + 4);
      As[arow][akc + 0] = __float2bfloat16(v0.x);
      As[arow][akc + 1] = __float2bfloat16(v0.y);
      As[arow][akc + 2] = __float2bfloat16(v0.z);
      As[arow][akc + 3] = __float2bfloat16(v0.w);
      As[arow][akc + 4] = __float2bfloat16(v1.x);
      As[arow][akc + 5] = __float2bfloat16(v1.y);
      As[arow][akc + 6] = __float2bfloat16(v1.z);
      As[arow][akc + 7] = __float2bfloat16(v1.w);
    } else {
#pragma unroll
      for (int i = 0; i < 8; ++i) {
        int k = k0 + akc + i;
        As[arow][akc + i] = (rok && k < K) ? __float2bfloat16(Ap[i]) : __float2bfloat16(0.f);
      }
    }
#pragma unroll
    for (int i = 0; i < 8; ++i) {
      int k = bkg + i;
      int kk = k0 + k;
      Bs[bn][k] = (kk < K) ? B[(size_t)kk * HID + col0 + bn] : __float2bfloat16(0.f);
    }
    __syncthreads();
    short8 bf = *(const short8*)&Bs[wave * 16 + mr][quad * 8];
#pragma unroll
    for (int r = 0; r < 4; ++r) {
      short8 af = *(const short8*)&As[r * 16 + mr][quad * 8];
      acc[r] = __builtin_amdgcn_mfma_f32_16x16x32_bf16(af, bf, acc[r], 0, 0, 0);
    }
    __syncthreads();
  }
  int col = col0 + wave * 16 + mr;
#pragma unroll
  for (int r = 0; r < 4; ++r) {
#pragma unroll
    for (int i = 0; i < 4; ++i) {
      int row = row0 + r * 16 + quad * 4 + i;
      if (row < M) C[(size_t)row * HID + col] = __float2bfloat16(acc[r][i]);
    }
  }
}

// ---------------- per-node attention logits (bf16 H, vectorized) ----------------

__global__ __launch_bounds__(256) void node_logits_kernel(const __hip_bfloat16* __restrict__ H,
    const float* __restrict__ a_src, const float* __restrict__ a_dst,
    float* __restrict__ en_src, float* __restrict__ en_dst, int N) {
  int idx = blockIdx.x * 256 + threadIdx.x;
  if (idx >= N * HEADS) return;
  int n = idx >> 3, h = idx & 7;
  const uint4* Hp = (const uint4*)(H + (size_t)n * HID + h * 32);
  const float* S = a_src + h * 32;
  const float* D = a_dst + h * 32;
  float es = 0.f, ed = 0.f;
#pragma unroll
  for (int j = 0; j < 4; ++j) {
    uint4 u = Hp[j];
    uint w[4] = {u.x, u.y, u.z, u.w};
#pragma unroll
    for (int p = 0; p < 4; ++p) {
      float lo = __uint_as_float(w[p] << 16);
      float hi = __uint_as_float(w[p] & 0xffff0000u);
      int c = j * 8 + p * 2;
      es += lo * S[c] + hi * S[c + 1];
      ed += lo * D[c] + hi * D[c + 1];
    }
  }
  en_src[idx] = es;
  en_dst[idx] = ed;
}

// ---------------- fused stats + aggregation: one wave per dst node ----------------
// lane l: head h = l>>3, slot = l&7 (pass1); channels 4l..4l+3 (pass2).

__global__ __launch_bounds__(256) void gat_agg_kernel(const __hip_bfloat16* __restrict__ H,
    const float* __restrict__ en_src, const float* __restrict__ en_dst,
    const int* __restrict__ rowptr, const int* __restrict__ csr_src,
    const float* __restrict__ bias, float* __restrict__ out, int apply_elu, int N) {
  int wave = threadIdx.x >> 6;
  int lane = threadIdx.x & 63;
  int n = blockIdx.x * 4 + wave;
  if (n >= N) return;
  int h = lane >> 3;
  int slot = lane & 7;
  int beg = rowptr[n], end = rowptr[n + 1];
  float ed = en_dst[n * HEADS + h];

  // ---- pass 1: per-head online max/sum, slot-strided ----
  float m = -1e30f, s = 0.f;
  for (int e = beg + slot; e < end; e += 8) {
    int src = csr_src[e];
    float v = en_src[src * HEADS + h] + ed;
    v = (v > 0.f) ? v : 0.2f * v;
    float mn = fmaxf(m, v);
    s = s * __expf(m - mn) + __expf(v - mn);
    m = mn;
  }
#pragma unroll
  for (int off = 1; off < 8; off <<= 1) {
    float mo = __shfl_xor(m, off);
    float so = __shfl_xor(s, off);
    float mn = fmaxf(m, mo);
    s = s * __expf(m - mn) + so * __expf(mo - mn);
    m = mn;
  }
  float rs = 1.f / (s + 1e-16f);

  // ---- pass 2: weighted gather-accumulate, 4 channels/lane, unroll x4 ----
  float4 acc = {0.f, 0.f, 0.f, 0.f};
  const __hip_bfloat16* Hc = H + lane * 4;
  for (int cs = beg; cs < end; cs += 64) {
    int cnt = min(64, end - cs);
    int myidx = csr_src[cs + ((lane < cnt) ? lane : (cnt - 1))];
    int i = 0;
    for (; i + 4 <= cnt; i += 4) {
      int s0 = __shfl(myidx, i);
      int s1 = __shfl(myidx, i + 1);
      int s2 = __shfl(myidx, i + 2);
      int s3 = __shfl(myidx, i + 3);
      uint2 g0 = *(const uint2*)(Hc + (size_t)s0 * HID);
      uint2 g1 = *(const uint2*)(Hc + (size_t)s1 * HID);
      uint2 g2 = *(const uint2*)(Hc + (size_t)s2 * HID);
      uint2 g3 = *(const uint2*)(Hc + (size_t)s3 * HID);
      float e0 = en_src[s0 * HEADS + h];
      float e1 = en_src[s1 * HEADS + h];
      float e2 = en_src[s2 * HEADS + h];
      float e3 = en_src[s3 * HEADS + h];
      uint2 gs[4] = {g0, g1, g2, g3};
      float es4[4] = {e0, e1, e2, e3};
#pragma unroll
      for (int j = 0; j < 4; ++j) {
        float v = es4[j] + ed;
        v = (v > 0.f) ? v : 0.2f * v;
        float w = __expf(v - m) * rs;
        uint2 g = gs[j];
        acc.x += w * __uint_as_float(g.x << 16);
        acc.y += w * __uint_as_float(g.x & 0xffff0000u);
        acc.z += w * __uint_as_float(g.y << 16);
        acc.w += w * __uint_as_float(g.y & 0xffff0000u);
      }
    }
    for (; i < cnt; ++i) {
      int s0 = __shfl(myidx, i);
      uint2 g = *(const uint2*)(Hc + (size_t)s0 * HID);
      float v = en_src[s0 * HEADS + h] + ed;
      v = (v > 0.f) ? v : 0.2f * v;
      float w = __expf(v - m) * rs;
      acc.x += w * __uint_as_float(g.x << 16);
      acc.y += w * __uint_as_float(g.x & 0xffff0000u);
      acc.z += w * __uint_as_float(g.y << 16);
      acc.w += w * __uint_as_float(g.y & 0xffff0000u);
    }
  }
  float4 bv = *(const float4*)(bias + lane * 4);
  float4 o;
  o.x = acc.x + bv.x; o.y = acc.y + bv.y; o.z = acc.z + bv.z; o.w = acc.w + bv.w;
  if (apply_elu) {
    o.x = (o.x > 0.f) ? o.x : expm1f(o.x);
    o.y = (o.y > 0.f) ? o.y : expm1f(o.y);
    o.z = (o.z > 0.f) ? o.z : expm1f(o.z);
    o.w = (o.w > 0.f) ? o.w : expm1f(o.w);
  }
  *(float4*)(out + (size_t)n * HID + lane * 4) = o;
}

// ---------------- JK max + final linear + log_softmax ----------------

__global__ __launch_bounds__(256) void final_kernel(const float* __restrict__ h0,
    const float* __restrict__ h1, const float* __restrict__ h2,
    const float* __restrict__ Wf, const float* __restrict__ bf,
    float* __restrict__ out, int N) {
  __shared__ float Wfs[HID * 40];
  __shared__ float jks[4][HID];
  int tid = threadIdx.x;
  for (int i = tid; i < HID * 40; i += 256) Wfs[i] = Wf[i];
  int sub = tid >> 6, lane = tid & 63;
  int n = blockIdx.x * 4 + sub;
  if (n < N) {
    const float4* p0 = (const float4*)(h0 + (size_t)n * HID);
    const float4* p1 = (const float4*)(h1 + (size_t)n * HID);
    const float4* p2 = (const float4*)(h2 + (size_t)n * HID);
    float4 a = p0[lane], b = p1[lane], cc = p2[lane];
    float4 r;
    r.x = fmaxf(fmaxf(a.x, b.x), cc.x);
    r.y = fmaxf(fmaxf(a.y, b.y), cc.y);
    r.z = fmaxf(fmaxf(a.z, b.z), cc.z);
    r.w = fmaxf(fmaxf(a.w, b.w), cc.w);
    *(float4*)&jks[sub][lane * 4] = r;
  }
  __syncthreads();
  float logit = -INFINITY;
  if (lane < 40 && n < N) {
    float accv = bf[lane];
#pragma unroll 8
    for (int k = 0; k < HID; ++k) accv += jks[sub][k] * Wfs[k * 40 + lane];
    logit = accv;
  }
  float mx = logit;
#pragma unroll
  for (int off = 32; off > 0; off >>= 1) mx = fmaxf(mx, __shfl_down(mx, off));
  mx = __shfl(mx, 0);
  float ex = (lane < 40 && n < N) ? __expf(logit - mx) : 0.f;
  float sm = ex;
#pragma unroll
  for (int off = 32; off > 0; off >>= 1) sm += __shfl_down(sm, off);
  sm = __shfl(sm, 0);
  if (lane < 40 && n < N) out[(size_t)n * 40 + lane] = logit - mx - __logf(sm);
}

// ---------------- launch ----------------

extern "C" void kernel_launch(void* const* d_in, const int* in_sizes, int n_in,
                              void* d_out, int out_size, void* d_ws, size_t ws_size,
                              hipStream_t stream) {
  (void)n_in; (void)out_size; (void)ws_size;
  const float* x   = (const float*)d_in[0];
  const int*   ei  = (const int*)d_in[1];
  const float* W0  = (const float*)d_in[2];
  const float* as0 = (const float*)d_in[3];
  const float* ad0 = (const float*)d_in[4];
  const float* b0  = (const float*)d_in[5];
  const float* W1  = (const float*)d_in[6];
  const float* as1 = (const float*)d_in[7];
  const float* ad1 = (const float*)d_in[8];
  const float* b1  = (const float*)d_in[9];
  const float* W2  = (const float*)d_in[10];
  const float* as2 = (const float*)d_in[11];
  const float* ad2 = (const float*)d_in[12];
  const float* b2  = (const float*)d_in[13];
  const float* Wf  = (const float*)d_in[14];
  const float* bf  = (const float*)d_in[15];
  float* out = (float*)d_out;

  const int E = in_sizes[1] / 2;
  const int IN_CH = in_sizes[2] / HID;
  const int N = in_sizes[0] / IN_CH;
  const int Etot = E + N;
  const size_t NM = (size_t)N * HID;
  const size_t NH = (size_t)N * HEADS;

  __hip_bfloat16* Htb = (__hip_bfloat16*)d_ws;
  float* fbase = (float*)(Htb + NM);
  float* h0   = fbase;
  float* h1   = fbase + NM;
  float* h2   = fbase + 2 * NM;
  float* en_s = fbase + 3 * NM;
  float* en_d = en_s + NH;
  int* rowptr  = (int*)(en_d + NH);
  int* deg     = rowptr + (N + 1);
  int* cursor  = deg + N;
  int* csr_src = cursor + N;
  __hip_bfloat16* Wb0 = (__hip_bfloat16*)(csr_src + Etot);
  __hip_bfloat16* Wb1 = Wb0 + (size_t)IN_CH * HID;
  __hip_bfloat16* Wb2 = Wb1 + HID * HID;

  hipMemsetAsync(deg, 0, sizeof(int) * N, stream);
  int ebl = (Etot + 255) / 256;
  deg_count_kernel<<<ebl, 256, 0, stream>>>(ei, deg, E, Etot);
  scan_kernel<<<1, 1024, 0, stream>>>(deg, rowptr, cursor, N);
  scatter_kernel<<<ebl, 256, 0, stream>>>(ei, cursor, csr_src, E, Etot);

  conv_bf16_kernel<<<(IN_CH * HID + 255) / 256, 256, 0, stream>>>(W0, Wb0, IN_CH * HID);
  conv_bf16_kernel<<<(HID * HID + 255) / 256, 256, 0, stream>>>(W1, Wb1, HID * HID);
  conv_bf16_kernel<<<(HID * HID + 255) / 256, 256, 0, stream>>>(W2, Wb2, HID * HID);

  dim3 ggrid(HID / 64, (N + 63) / 64);
  int lblocks = (N * HEADS + 255) / 256;
  int ablocks = (N + 3) / 4;

  // layer 0
  gemm_bf16<<<ggrid, 256, 0, stream>>>(x, Wb0, Htb, N, IN_CH);
  node_logits_kernel<<<lblocks, 256, 0, stream>>>(Htb, as0, ad0, en_s, en_d, N);
  gat_agg_kernel<<<ablocks, 256, 0, stream>>>(Htb, en_s, en_d, rowptr, csr_src, b0, h0, 1, N);
  // layer 1
  gemm_bf16<<<ggrid, 256, 0, stream>>>(h0, Wb1, Htb, N, HID);
  node_logits_kernel<<<lblocks, 256, 0, stream>>>(Htb, as1, ad1, en_s, en_d, N);
  gat_agg_kernel<<<ablocks, 256, 0, stream>>>(Htb, en_s, en_d, rowptr, csr_src, b1, h1, 1, N);
  // layer 2
  gemm_bf16<<<ggrid, 256, 0, stream>>>(h1, Wb2, Htb, N, HID);
  node_logits_kernel<<<lblocks, 256, 0, stream>>>(Htb, as2, ad2, en_s, en_d, N);
  gat_agg_kernel<<<ablocks, 256, 0, stream>>>(Htb, en_s, en_d, rowptr, csr_src, b2, h2, 0, N);

  final_kernel<<<(N + 3) / 4, 256, 0, stream>>>(h0, h1, h2, Wf, bf, out, N);
}

// Round 4
// 2290.738 us; speedup vs baseline: 1.8765x; 1.1054x over previous
//
#include <hip/hip_runtime.h>
#include <hip/hip_bf16.h>
#include <math.h>

#define HID 256
#define HEADS 8
#define KP0 512

typedef __attribute__((ext_vector_type(8))) short short8;
typedef __attribute__((ext_vector_type(4))) float floatx4;

__device__ __forceinline__ void gl_lds16(const void* g, void* l) {
  __builtin_amdgcn_global_load_lds(
      (const __attribute__((address_space(1))) void*)g,
      (__attribute__((address_space(3))) void*)l, 16, 0, 0);
}

// ---------------- CSR build ----------------

__global__ __launch_bounds__(256) void deg_count_kernel(const int* __restrict__ ei,
    int* __restrict__ deg, int E, int Etot) {
  int idx = blockIdx.x * 256 + threadIdx.x;
  if (idx >= Etot) return;
  int d = (idx < E) ? ei[E + idx] : (idx - E);
  atomicAdd(&deg[d], 1);
}

__global__ __launch_bounds__(1024) void scan_kernel(const int* __restrict__ deg,
    int* __restrict__ rowptr, int* __restrict__ cursor, int N) {
  __shared__ int sums[1024];
  int t = threadIdx.x;
  int chunk = (N + 1023) / 1024;
  int lo = t * chunk, hi = min(N, lo + chunk);
  int s = 0;
  for (int i = lo; i < hi; ++i) s += deg[i];
  sums[t] = s;
  __syncthreads();
  for (int off = 1; off < 1024; off <<= 1) {
    int v = (t >= off) ? sums[t - off] : 0;
    __syncthreads();
    sums[t] += v;
    __syncthreads();
  }
  int prefix = (t == 0) ? 0 : sums[t - 1];
  for (int i = lo; i < hi; ++i) {
    rowptr[i] = prefix;
    cursor[i] = prefix;
    prefix += deg[i];
  }
  if (t == 1023) rowptr[N] = sums[1023];
}

__global__ __launch_bounds__(256) void scatter_kernel(const int* __restrict__ ei,
    int* __restrict__ cursor, int* __restrict__ csr_src, int E, int Etot) {
  int idx = blockIdx.x * 256 + threadIdx.x;
  if (idx >= Etot) return;
  int s, d;
  if (idx < E) { s = ei[idx]; d = ei[E + idx]; }
  else { s = idx - E; d = s; }
  int pos = atomicAdd(&cursor[d], 1);
  csr_src[pos] = s;
}

// ---------------- input conversions ----------------

// x[M][500] fp32 -> xb[Mp][512] bf16 (k-pad zeros); rows >= M untouched (garbage ok)
__global__ __launch_bounds__(256) void conv_x_kernel(const float* __restrict__ x,
    __hip_bfloat16* __restrict__ xb, int M, int K) {
  int idx = blockIdx.x * 256 + threadIdx.x;
  if (idx >= M * KP0) return;
  int n = idx >> 9, k = idx & (KP0 - 1);
  xb[idx] = __float2bfloat16((k < K) ? x[(size_t)n * K + k] : 0.f);
}

// W[K][256] fp32 -> Wt[256][Kp] bf16 transposed, k-pad zeros
__global__ __launch_bounds__(256) void convT_w_kernel(const float* __restrict__ W,
    __hip_bfloat16* __restrict__ Wt, int K, int Kp) {
  int idx = blockIdx.x * 256 + threadIdx.x;
  if (idx >= 256 * Kp) return;
  int n = idx / Kp, k = idx - n * Kp;
  Wt[idx] = __float2bfloat16((k < K) ? W[(size_t)k * 256 + n] : 0.f);
}

// ---------------- bf16 MFMA GEMM (m97-style): C[M,256] = A[Mp,Kp] @ Bt[256,Kp]^T ----
// 128x128 tile, BK=32, 4 waves each 64x64 subtile (4x4 frags of 16x16x32).

__global__ __launch_bounds__(256) void gemm_mfma(const __hip_bfloat16* __restrict__ A,
    const __hip_bfloat16* __restrict__ Bt, __hip_bfloat16* __restrict__ C,
    int M, int Kp) {
  __shared__ __align__(16) __hip_bfloat16 As[128][32];
  __shared__ __align__(16) __hip_bfloat16 Bs[128][32];
  int tid = threadIdx.x;
  int wave = tid >> 6, lane = tid & 63;
  int quad = lane >> 4, mr = lane & 15;
  int row0 = blockIdx.x * 128, col0 = blockIdx.y * 128;
  int wm = (wave & 1) * 64, wn = (wave >> 1) * 64;
  floatx4 acc[4][4] = {};

  int srow = (lane >> 2);            // 0..15 within 16-row group
  int kslot = lane & 3;
  // XOR swizzle: LDS[row][slot] holds global k-chunk (slot ^ (row&3))
  int kc = (kslot ^ (srow & 3)) * 8;

  for (int k0 = 0; k0 < Kp; k0 += 32) {
#pragma unroll
    for (int j = 0; j < 2; ++j) {
      int r = wave * 32 + j * 16 + srow;
      gl_lds16(A + (size_t)(row0 + r) * Kp + k0 + kc, &As[wave * 32 + j * 16][0]);
      gl_lds16(Bt + (size_t)(col0 + r) * Kp + k0 + kc, &Bs[wave * 32 + j * 16][0]);
    }
    __syncthreads();
    short8 af[4], bfr[4];
#pragma unroll
    for (int r = 0; r < 4; ++r) {
      int row = wm + r * 16 + mr;
      af[r] = *(const short8*)&As[row][(quad ^ (row & 3)) * 8];
      int col = wn + r * 16 + mr;
      bfr[r] = *(const short8*)&Bs[col][(quad ^ (col & 3)) * 8];
    }
#pragma unroll
    for (int r = 0; r < 4; ++r)
#pragma unroll
      for (int c = 0; c < 4; ++c)
        acc[r][c] = __builtin_amdgcn_mfma_f32_16x16x32_bf16(af[r], bfr[c], acc[r][c], 0, 0, 0);
    __syncthreads();
  }
#pragma unroll
  for (int r = 0; r < 4; ++r) {
#pragma unroll
    for (int c = 0; c < 4; ++c) {
#pragma unroll
      for (int i = 0; i < 4; ++i) {
        int row = row0 + wm + r * 16 + quad * 4 + i;
        int col = col0 + wn + c * 16 + mr;
        if (row < M) C[(size_t)row * HID + col] = __float2bfloat16(acc[r][c][i]);
      }
    }
  }
}

// ---------------- per-node attention logits (bf16 H, vectorized) ----------------

__global__ __launch_bounds__(256) void node_logits_kernel(const __hip_bfloat16* __restrict__ H,
    const float* __restrict__ a_src, const float* __restrict__ a_dst,
    float* __restrict__ en_src, float* __restrict__ en_dst, int N) {
  int idx = blockIdx.x * 256 + threadIdx.x;
  if (idx >= N * HEADS) return;
  int n = idx >> 3, h = idx & 7;
  const uint4* Hp = (const uint4*)(H + (size_t)n * HID + h * 32);
  const float* S = a_src + h * 32;
  const float* D = a_dst + h * 32;
  float es = 0.f, ed = 0.f;
#pragma unroll
  for (int j = 0; j < 4; ++j) {
    uint4 u = Hp[j];
    uint w[4] = {u.x, u.y, u.z, u.w};
#pragma unroll
    for (int p = 0; p < 4; ++p) {
      float lo = __uint_as_float(w[p] << 16);
      float hi = __uint_as_float(w[p] & 0xffff0000u);
      int c = j * 8 + p * 2;
      es += lo * S[c] + hi * S[c + 1];
      ed += lo * D[c] + hi * D[c + 1];
    }
  }
  en_src[idx] = es;
  en_dst[idx] = ed;
}

// ---------------- fused stats + aggregation: one wave per dst node ----------------

__global__ __launch_bounds__(256) void gat_agg_kernel(const __hip_bfloat16* __restrict__ H,
    const float* __restrict__ en_src, const float* __restrict__ en_dst,
    const int* __restrict__ rowptr, const int* __restrict__ csr_src,
    const float* __restrict__ bias, float* __restrict__ out,
    __hip_bfloat16* __restrict__ hb, int apply_elu, int N) {
  int wave = threadIdx.x >> 6;
  int lane = threadIdx.x & 63;
  int n = blockIdx.x * 4 + wave;
  if (n >= N) return;
  int h = lane >> 3;
  int slot = lane & 7;
  int beg = rowptr[n], end = rowptr[n + 1];
  float ed = en_dst[n * HEADS + h];

  float m = -1e30f, s = 0.f;
  for (int e = beg + slot; e < end; e += 8) {
    int src = csr_src[e];
    float v = en_src[src * HEADS + h] + ed;
    v = (v > 0.f) ? v : 0.2f * v;
    float mn = fmaxf(m, v);
    s = s * __expf(m - mn) + __expf(v - mn);
    m = mn;
  }
#pragma unroll
  for (int off = 1; off < 8; off <<= 1) {
    float mo = __shfl_xor(m, off);
    float so = __shfl_xor(s, off);
    float mn = fmaxf(m, mo);
    s = s * __expf(m - mn) + so * __expf(mo - mn);
    m = mn;
  }
  float rs = 1.f / (s + 1e-16f);

  float4 acc = {0.f, 0.f, 0.f, 0.f};
  const __hip_bfloat16* Hc = H + lane * 4;
  for (int cs = beg; cs < end; cs += 64) {
    int cnt = min(64, end - cs);
    int myidx = csr_src[cs + ((lane < cnt) ? lane : (cnt - 1))];
    int i = 0;
    for (; i + 4 <= cnt; i += 4) {
      int s0 = __shfl(myidx, i);
      int s1 = __shfl(myidx, i + 1);
      int s2 = __shfl(myidx, i + 2);
      int s3 = __shfl(myidx, i + 3);
      uint2 g0 = *(const uint2*)(Hc + (size_t)s0 * HID);
      uint2 g1 = *(const uint2*)(Hc + (size_t)s1 * HID);
      uint2 g2 = *(const uint2*)(Hc + (size_t)s2 * HID);
      uint2 g3 = *(const uint2*)(Hc + (size_t)s3 * HID);
      float e0 = en_src[s0 * HEADS + h];
      float e1 = en_src[s1 * HEADS + h];
      float e2 = en_src[s2 * HEADS + h];
      float e3 = en_src[s3 * HEADS + h];
      uint2 gs[4] = {g0, g1, g2, g3};
      float es4[4] = {e0, e1, e2, e3};
#pragma unroll
      for (int j = 0; j < 4; ++j) {
        float v = es4[j] + ed;
        v = (v > 0.f) ? v : 0.2f * v;
        float w = __expf(v - m) * rs;
        uint2 g = gs[j];
        acc.x += w * __uint_as_float(g.x << 16);
        acc.y += w * __uint_as_float(g.x & 0xffff0000u);
        acc.z += w * __uint_as_float(g.y << 16);
        acc.w += w * __uint_as_float(g.y & 0xffff0000u);
      }
    }
    for (; i < cnt; ++i) {
      int s0 = __shfl(myidx, i);
      uint2 g = *(const uint2*)(Hc + (size_t)s0 * HID);
      float v = en_src[s0 * HEADS + h] + ed;
      v = (v > 0.f) ? v : 0.2f * v;
      float w = __expf(v - m) * rs;
      acc.x += w * __uint_as_float(g.x << 16);
      acc.y += w * __uint_as_float(g.x & 0xffff0000u);
      acc.z += w * __uint_as_float(g.y << 16);
      acc.w += w * __uint_as_float(g.y & 0xffff0000u);
    }
  }
  float4 bv = *(const float4*)(bias + lane * 4);
  float4 o;
  o.x = acc.x + bv.x; o.y = acc.y + bv.y; o.z = acc.z + bv.z; o.w = acc.w + bv.w;
  if (apply_elu) {
    o.x = (o.x > 0.f) ? o.x : expm1f(o.x);
    o.y = (o.y > 0.f) ? o.y : expm1f(o.y);
    o.z = (o.z > 0.f) ? o.z : expm1f(o.z);
    o.w = (o.w > 0.f) ? o.w : expm1f(o.w);
  }
  *(float4*)(out + (size_t)n * HID + lane * 4) = o;
  union { __hip_bfloat16 hh[4]; uint2 u; } pk;
  pk.hh[0] = __float2bfloat16(o.x);
  pk.hh[1] = __float2bfloat16(o.y);
  pk.hh[2] = __float2bfloat16(o.z);
  pk.hh[3] = __float2bfloat16(o.w);
  *(uint2*)(hb + (size_t)n * HID + lane * 4) = pk.u;
}

// ---------------- JK max + final linear + log_softmax ----------------

__global__ __launch_bounds__(256) void final_kernel(const float* __restrict__ h0,
    const float* __restrict__ h1, const float* __restrict__ h2,
    const float* __restrict__ Wf, const float* __restrict__ bf,
    float* __restrict__ out, int N) {
  __shared__ float Wfs[HID * 40];
  __shared__ float jks[4][HID];
  int tid = threadIdx.x;
  for (int i = tid; i < HID * 40; i += 256) Wfs[i] = Wf[i];
  int sub = tid >> 6, lane = tid & 63;
  int n = blockIdx.x * 4 + sub;
  if (n < N) {
    const float4* p0 = (const float4*)(h0 + (size_t)n * HID);
    const float4* p1 = (const float4*)(h1 + (size_t)n * HID);
    const float4* p2 = (const float4*)(h2 + (size_t)n * HID);
    float4 a = p0[lane], b = p1[lane], cc = p2[lane];
    float4 r;
    r.x = fmaxf(fmaxf(a.x, b.x), cc.x);
    r.y = fmaxf(fmaxf(a.y, b.y), cc.y);
    r.z = fmaxf(fmaxf(a.z, b.z), cc.z);
    r.w = fmaxf(fmaxf(a.w, b.w), cc.w);
    *(float4*)&jks[sub][lane * 4] = r;
  }
  __syncthreads();
  float logit = -INFINITY;
  if (lane < 40 && n < N) {
    float accv = bf[lane];
#pragma unroll 8
    for (int k = 0; k < HID; ++k) accv += jks[sub][k] * Wfs[k * 40 + lane];
    logit = accv;
  }
  float mx = logit;
#pragma unroll
  for (int off = 32; off > 0; off >>= 1) mx = fmaxf(mx, __shfl_down(mx, off));
  mx = __shfl(mx, 0);
  float ex = (lane < 40 && n < N) ? __expf(logit - mx) : 0.f;
  float sm = ex;
#pragma unroll
  for (int off = 32; off > 0; off >>= 1) sm += __shfl_down(sm, off);
  sm = __shfl(sm, 0);
  if (lane < 40 && n < N) out[(size_t)n * 40 + lane] = logit - mx - __logf(sm);
}

// ---------------- launch ----------------

extern "C" void kernel_launch(void* const* d_in, const int* in_sizes, int n_in,
                              void* d_out, int out_size, void* d_ws, size_t ws_size,
                              hipStream_t stream) {
  (void)n_in; (void)out_size; (void)ws_size;
  const float* x   = (const float*)d_in[0];
  const int*   ei  = (const int*)d_in[1];
  const float* W0  = (const float*)d_in[2];
  const float* as0 = (const float*)d_in[3];
  const float* ad0 = (const float*)d_in[4];
  const float* b0  = (const float*)d_in[5];
  const float* W1  = (const float*)d_in[6];
  const float* as1 = (const float*)d_in[7];
  const float* ad1 = (const float*)d_in[8];
  const float* b1  = (const float*)d_in[9];
  const float* W2  = (const float*)d_in[10];
  const float* as2 = (const float*)d_in[11];
  const float* ad2 = (const float*)d_in[12];
  const float* b2  = (const float*)d_in[13];
  const float* Wf  = (const float*)d_in[14];
  const float* bf  = (const float*)d_in[15];
  float* out = (float*)d_out;

  const int E = in_sizes[1] / 2;
  const int IN_CH = in_sizes[2] / HID;      // 500
  const int N = in_sizes[0] / IN_CH;        // 100000
  const int Etot = E + N;
  const int Mp = ((N + 127) / 128) * 128;   // 100096
  const size_t NM = (size_t)N * HID;

  __hip_bfloat16* xb  = (__hip_bfloat16*)d_ws;            // Mp*KP0
  __hip_bfloat16* Htb = xb + (size_t)Mp * KP0;            // N*HID
  __hip_bfloat16* hb  = Htb + NM;                         // Mp*HID
  __hip_bfloat16* Wt0 = hb + (size_t)Mp * HID;            // 256*KP0
  __hip_bfloat16* Wt1 = Wt0 + 256 * KP0;                  // 256*256
  __hip_bfloat16* Wt2 = Wt1 + 256 * 256;
  float* fbase = (float*)(Wt2 + 256 * 256);
  float* h0   = fbase;
  float* h1   = fbase + NM;
  float* h2   = fbase + 2 * NM;
  float* en_s = fbase + 3 * NM;
  float* en_d = en_s + (size_t)N * HEADS;
  int* rowptr  = (int*)(en_d + (size_t)N * HEADS);
  int* deg     = rowptr + (N + 1);
  int* cursor  = deg + N;
  int* csr_src = cursor + N;

  hipMemsetAsync(deg, 0, sizeof(int) * N, stream);
  int ebl = (Etot + 255) / 256;
  deg_count_kernel<<<ebl, 256, 0, stream>>>(ei, deg, E, Etot);
  scan_kernel<<<1, 1024, 0, stream>>>(deg, rowptr, cursor, N);
  scatter_kernel<<<ebl, 256, 0, stream>>>(ei, cursor, csr_src, E, Etot);

  conv_x_kernel<<<((size_t)N * KP0 + 255) / 256, 256, 0, stream>>>(x, xb, N, IN_CH);
  convT_w_kernel<<<(256 * KP0 + 255) / 256, 256, 0, stream>>>(W0, Wt0, IN_CH, KP0);
  convT_w_kernel<<<(256 * 256 + 255) / 256, 256, 0, stream>>>(W1, Wt1, HID, HID);
  convT_w_kernel<<<(256 * 256 + 255) / 256, 256, 0, stream>>>(W2, Wt2, HID, HID);

  dim3 ggrid(Mp / 128, 2);
  int lblocks = (N * HEADS + 255) / 256;
  int ablocks = (N + 3) / 4;

  // layer 0
  gemm_mfma<<<ggrid, 256, 0, stream>>>(xb, Wt0, Htb, N, KP0);
  node_logits_kernel<<<lblocks, 256, 0, stream>>>(Htb, as0, ad0, en_s, en_d, N);
  gat_agg_kernel<<<ablocks, 256, 0, stream>>>(Htb, en_s, en_d, rowptr, csr_src, b0, h0, hb, 1, N);
  // layer 1
  gemm_mfma<<<ggrid, 256, 0, stream>>>(hb, Wt1, Htb, N, HID);
  node_logits_kernel<<<lblocks, 256, 0, stream>>>(Htb, as1, ad1, en_s, en_d, N);
  gat_agg_kernel<<<ablocks, 256, 0, stream>>>(Htb, en_s, en_d, rowptr, csr_src, b1, h1, hb, 1, N);
  // layer 2
  gemm_mfma<<<ggrid, 256, 0, stream>>>(hb, Wt2, Htb, N, HID);
  node_logits_kernel<<<lblocks, 256, 0, stream>>>(Htb, as2, ad2, en_s, en_d, N);
  gat_agg_kernel<<<ablocks, 256, 0, stream>>>(Htb, en_s, en_d, rowptr, csr_src, b2, h2, hb, 0, N);

  final_kernel<<<(N + 3) / 4, 256, 0, stream>>>(h0, h1, h2, Wf, bf, out, N);
}